// Round 1
// baseline (270.908 us; speedup 1.0000x reference)
//
#include <hip/hip_runtime.h>
#include <cstdint>

typedef unsigned uint;

// d_ws layout (32-bit words):
//   [0,144)      w1 signs as +-1.0f  (float)
//   [144,432)    w2 packed: w2p[oc*9+k], bit ic (16 bits used)
//   [432,720)    w3 packed: w3p[oc*9+k], bit ic (32 bits)
//   [720,5560)   wfc packed+expanded: wfcp[o*484 + Y*22+X], bit c =
//                sign(wfc[o,c*121 + (Y/2)*11 + (X/2)])
static constexpr int WS_W1 = 0;
static constexpr int WS_W2 = 144;
static constexpr int WS_W3 = 432;
static constexpr int WS_FC = 720;
static constexpr int WS_TOT = 5560;

__global__ __launch_bounds__(256) void pack_kernel(
    const float* __restrict__ w1, const float* __restrict__ w2,
    const float* __restrict__ w3, const float* __restrict__ wfc,
    uint* __restrict__ wsu)
{
    int gid = blockIdx.x * 256 + threadIdx.x;
    if (gid < 144) {
        ((float*)wsu)[WS_W1 + gid] = (w1[gid] >= 0.f) ? 1.f : -1.f;
    } else if (gid < 432) {
        int e = gid - 144; int oc = e / 9, k = e % 9;
        uint bits = 0;
        for (int ic = 0; ic < 16; ++ic)
            bits |= (w2[(oc*16 + ic)*9 + k] >= 0.f ? 1u : 0u) << ic;
        wsu[WS_W2 + e] = bits;
    } else if (gid < 720) {
        int e = gid - 432; int oc = e / 9, k = e % 9;
        uint bits = 0;
        for (int ic = 0; ic < 32; ++ic)
            bits |= (w3[(oc*32 + ic)*9 + k] >= 0.f ? 1u : 0u) << ic;
        wsu[WS_W3 + e] = bits;
    } else if (gid < WS_TOT) {
        int e = gid - 720; int o = e / 484, p = e % 484;
        int Y = p / 22, X = p % 22;
        const float* base = wfc + o*3872 + (Y >> 1)*11 + (X >> 1);
        uint bits = 0;
        for (int c = 0; c < 32; ++c)
            bits |= (base[c*121] >= 0.f ? 1u : 0u) << c;
        wsu[WS_FC + e] = bits;
    }
}

__global__ __launch_bounds__(256) void binet_kernel(
    const float* __restrict__ x, const uint* __restrict__ wsu,
    const float* __restrict__ bfc, float* __restrict__ out)
{
    __shared__ float xs[784];     // 28x28 input image
    __shared__ uint  h1p[676];    // 26x26, 16 channel bits
    __shared__ uint  h2p[576];    // 24x24, 32 channel bits
    __shared__ uint  h3p[484];    // 22x22, 32 channel bits
    __shared__ int   red[4][10];
    __shared__ float lg[10];

    const int t = threadIdx.x;
    const int img = blockIdx.x;
    const float* wf = (const float*)wsu;   // w1 signs

    // ---- load image ----
    {
        const float* xin = x + (size_t)img * 784;
        for (int i = t; i < 784; i += 256) xs[i] = xin[i];
    }
    __syncthreads();

    // ---- conv1 (fp32 data, fp64 accumulate -> exact sign) + binarize ----
    {
        const int p0 = t, p1 = t + 256, p2 = t + 512;
        const bool has2 = (p2 < 676);
        const int y0 = p0 / 26, x0 = p0 % 26;
        const int y1 = p1 / 26, x1 = p1 % 26;
        const int y2 = has2 ? p2 / 26 : 0, x2 = has2 ? p2 % 26 : 0;
        float xv0[9], xv1[9], xv2[9];
        #pragma unroll
        for (int ky = 0; ky < 3; ++ky)
            #pragma unroll
            for (int kx = 0; kx < 3; ++kx) {
                xv0[ky*3+kx] = xs[(y0+ky)*28 + x0 + kx];
                xv1[ky*3+kx] = xs[(y1+ky)*28 + x1 + kx];
                xv2[ky*3+kx] = xs[(y2+ky)*28 + x2 + kx];
            }
        uint b0 = 0, b1 = 0, b2 = 0;
        for (int oc = 0; oc < 16; ++oc) {
            double s0 = 0.0, s1 = 0.0, s2 = 0.0;
            #pragma unroll
            for (int k = 0; k < 9; ++k) {
                double w = (double)wf[oc*9 + k];   // uniform -> scalar load
                s0 += (double)xv0[k] * w;
                s1 += (double)xv1[k] * w;
                s2 += (double)xv2[k] * w;
            }
            b0 |= (uint)(s0 >= 0.0) << oc;
            b1 |= (uint)(s1 >= 0.0) << oc;
            b2 |= (uint)(s2 >= 0.0) << oc;
        }
        h1p[p0] = b0;
        h1p[p1] = b1;
        if (has2) h1p[p2] = b2;
    }
    __syncthreads();

    // ---- conv2: 26x26x16 -> 24x24x32, xnor-popcount ----
    if (t < 192) {                       // 24 rows x 8 col-triples
        const int y = t >> 3, c0 = 3 * (t & 7);
        uint hrow[3][5];
        #pragma unroll
        for (int ky = 0; ky < 3; ++ky)
            #pragma unroll
            for (int c = 0; c < 5; ++c)
                hrow[ky][c] = h1p[(y+ky)*26 + c0 + c];
        uint b0 = 0, b1 = 0, b2 = 0;
        for (int oc = 0; oc < 32; ++oc) {
            int d0 = 0, d1 = 0, d2 = 0;
            #pragma unroll
            for (int ky = 0; ky < 3; ++ky)
                #pragma unroll
                for (int kx = 0; kx < 3; ++kx) {
                    uint w = wsu[WS_W2 + oc*9 + ky*3 + kx];  // uniform
                    d0 += __popc(hrow[ky][kx    ] ^ w);
                    d1 += __popc(hrow[ky][kx + 1] ^ w);
                    d2 += __popc(hrow[ky][kx + 2] ^ w);
                }
            // pre-act = 144 - 2*d ; binarize(>=0) <=> d <= 72
            b0 |= (uint)(d0 <= 72) << oc;
            b1 |= (uint)(d1 <= 72) << oc;
            b2 |= (uint)(d2 <= 72) << oc;
        }
        h2p[y*24 + c0    ] = b0;
        h2p[y*24 + c0 + 1] = b1;
        h2p[y*24 + c0 + 2] = b2;
    }
    __syncthreads();

    // ---- conv3: 24x24x32 -> 22x22x32 ----
    if (t < 242) {                       // 22 rows x 11 col-pairs
        const int y = t / 11, c0 = 2 * (t % 11);
        uint hrow[3][4];
        #pragma unroll
        for (int ky = 0; ky < 3; ++ky)
            #pragma unroll
            for (int c = 0; c < 4; ++c)
                hrow[ky][c] = h2p[(y+ky)*24 + c0 + c];
        uint b0 = 0, b1 = 0;
        for (int oc = 0; oc < 32; ++oc) {
            int d0 = 0, d1 = 0;
            #pragma unroll
            for (int ky = 0; ky < 3; ++ky)
                #pragma unroll
                for (int kx = 0; kx < 3; ++kx) {
                    uint w = wsu[WS_W3 + oc*9 + ky*3 + kx];  // uniform
                    d0 += __popc(hrow[ky][kx    ] ^ w);
                    d1 += __popc(hrow[ky][kx + 1] ^ w);
                }
            // pre-act = 288 - 2*d ; binarize <=> d <= 144
            b0 |= (uint)(d0 <= 144) << oc;
            b1 |= (uint)(d1 <= 144) << oc;
        }
        h3p[y*22 + c0    ] = b0;
        h3p[y*22 + c0 + 1] = b1;
    }
    __syncthreads();

    // ---- avgpool + FC folded into one binary dot product ----
    int acc[10];
    #pragma unroll
    for (int o = 0; o < 10; ++o) acc[o] = 0;
    for (int p = t; p < 484; p += 256) {
        uint h = h3p[p];
        const uint* wp = wsu + WS_FC + p;
        #pragma unroll
        for (int o = 0; o < 10; ++o)
            acc[o] += __popc(h ^ wp[o*484]);
    }
    #pragma unroll
    for (int o = 0; o < 10; ++o) {
        int v = acc[o];
        v += __shfl_down(v, 32); v += __shfl_down(v, 16);
        v += __shfl_down(v, 8);  v += __shfl_down(v, 4);
        v += __shfl_down(v, 2);  v += __shfl_down(v, 1);
        acc[o] = v;
    }
    const int wave = t >> 6;
    if ((t & 63) == 0) {
        #pragma unroll
        for (int o = 0; o < 10; ++o) red[wave][o] = acc[o];
    }
    __syncthreads();
    if (t < 10) {
        int S = red[0][t] + red[1][t] + red[2][t] + red[3][t];
        // sum over 15488 bits = 15488 - 2S ; pooled dot = 0.25 * that
        lg[t] = 0.25f * (float)(15488 - 2*S) + bfc[t];
    }
    __syncthreads();
    if (t < 10) {
        float m = lg[0];
        #pragma unroll
        for (int o = 1; o < 10; ++o) m = fmaxf(m, lg[o]);
        float se = 0.f;
        #pragma unroll
        for (int o = 0; o < 10; ++o) se += expf(lg[o] - m);
        out[(size_t)img*10 + t] = lg[t] - m - logf(se);
    }
}

extern "C" void kernel_launch(void* const* d_in, const int* in_sizes, int n_in,
                              void* d_out, int out_size, void* d_ws, size_t ws_size,
                              hipStream_t stream)
{
    const float* x   = (const float*)d_in[0];
    const float* w1  = (const float*)d_in[1];
    const float* w2  = (const float*)d_in[2];
    const float* w3  = (const float*)d_in[3];
    const float* wfc = (const float*)d_in[4];
    const float* bfc = (const float*)d_in[5];
    float* out = (float*)d_out;
    uint* wsu  = (uint*)d_ws;

    const int B = in_sizes[0] / 784;   // 8192

    hipLaunchKernelGGL(pack_kernel, dim3(22), dim3(256), 0, stream,
                       w1, w2, w3, wfc, wsu);
    hipLaunchKernelGGL(binet_kernel, dim3(B), dim3(256), 0, stream,
                       x, wsu, bfc, out);
}

// Round 2
// 191.821 us; speedup vs baseline: 1.4123x; 1.4123x over previous
//
#include <hip/hip_runtime.h>
#include <cstdint>

typedef unsigned uint;
typedef int v4i  __attribute__((ext_vector_type(4)));
typedef int v16i __attribute__((ext_vector_type(16)));

// d_ws word layout:
//   [0,144)       w1 signs as +-1.0f
//   [144,1424)    W2B: conv2 B-frags, frag f=s*64+l, 4 words each (16 i8)
//   [1424,3728)   W3B: conv3 B-frags, frag f=s*64+l, 4 words each
//   [3728,8568)   wfc packed+expanded to 22x22 grid (10*484 words)
static constexpr int WS_W2B = 144;
static constexpr int WS_W3B = 1424;
static constexpr int WS_FC  = 3728;

// LDS byte offsets
static constexpr int L_H2  = 0;       // h2 i8 [576 pos][32 ic]; xs overlaid here in conv1
static constexpr int L_H1  = 18432;   // h1 i8 [676 pos][16 ic]; h3 words overlaid in conv3+
static constexpr int L_RED = 29248;   // int[4][10]
static constexpr int L_LG  = 29408;   // float[10]

__global__ __launch_bounds__(256) void pack_kernel(
    const float* __restrict__ w1, const float* __restrict__ w2,
    const float* __restrict__ w3, const float* __restrict__ wfc,
    uint* __restrict__ wsu)
{
    int gid = blockIdx.x * 256 + threadIdx.x;
    if (gid < 144) {
        ((float*)wsu)[gid] = (w1[gid] >= 0.f) ? 1.f : -1.f;
    } else if (gid < 464) {
        // conv2 B fragment: oc = l&31, tap = 2s + (l>>5), ic = e (K = tap*16+ic)
        int f = gid - 144, s = f >> 6, l = f & 63;
        int oc = l & 31, tap = s * 2 + (l >> 5);
        uint w[4] = {0u, 0u, 0u, 0u};
        if (tap < 9) {
            for (int e = 0; e < 16; ++e) {
                uint b = (w2[(oc * 16 + e) * 9 + tap] >= 0.f) ? 0x01u : 0xFFu;
                w[e >> 2] |= b << (8 * (e & 3));
            }
        }
        for (int j = 0; j < 4; ++j) wsu[WS_W2B + f * 4 + j] = w[j];
    } else if (gid < 1040) {
        // conv3 B fragment: oc = l&31, tap = s, ic = (l>>5)*16 + e (K = tap*32+ic)
        int f = gid - 464, s = f >> 6, l = f & 63;
        int oc = l & 31, icb = (l >> 5) * 16;
        uint w[4] = {0u, 0u, 0u, 0u};
        for (int e = 0; e < 16; ++e) {
            uint b = (w3[(oc * 32 + icb + e) * 9 + s] >= 0.f) ? 0x01u : 0xFFu;
            w[e >> 2] |= b << (8 * (e & 3));
        }
        for (int j = 0; j < 4; ++j) wsu[WS_W3B + f * 4 + j] = w[j];
    } else if (gid < 5880) {
        int f = gid - 1040, o = f / 484, p = f % 484;
        int Y = p / 22, X = p % 22;
        const float* base = wfc + o * 3872 + (Y >> 1) * 11 + (X >> 1);
        uint bits = 0;
        for (int c = 0; c < 32; ++c)
            bits |= (base[c * 121] >= 0.f ? 1u : 0u) << c;
        wsu[WS_FC + f] = bits;
    }
}

__global__ __launch_bounds__(256) void binet_kernel(
    const float* __restrict__ x, const uint* __restrict__ wsu,
    const float* __restrict__ bfc, float* __restrict__ out)
{
    __shared__ __align__(16) unsigned char lds[29456];
    const int t = threadIdx.x;
    const int img = blockIdx.x;
    const int l = t & 63, wave = t >> 6, half = l >> 5;

    float* xs = (float*)(lds + L_H2);
    signed char* h1 = (signed char*)(lds + L_H1);
    signed char* h2 = (signed char*)(lds + L_H2);
    uint* h3 = (uint*)(lds + L_H1);
    int (*red)[10] = (int(*)[10])(lds + L_RED);
    float* lg = (float*)(lds + L_LG);

    // ---- load image ----
    {
        const float* xin = x + (size_t)img * 784;
        for (int i = t; i < 784; i += 256) xs[i] = xin[i];
    }
    __syncthreads();

    // ---- conv1: fp32 fast path, fp64 fallback near zero; emit i8 +-1 ----
    {
        const float* wf = (const float*)wsu;
        const int p0 = t, p1 = t + 256, p2 = t + 512;
        const bool has2 = (p2 < 676);
        const int y0 = p0 / 26, x0 = p0 % 26;
        const int y1 = p1 / 26, x1 = p1 % 26;
        const int y2 = has2 ? p2 / 26 : 0, x2 = has2 ? p2 % 26 : 0;
        float xv0[9], xv1[9], xv2[9];
        #pragma unroll
        for (int ky = 0; ky < 3; ++ky)
            #pragma unroll
            for (int kx = 0; kx < 3; ++kx) {
                xv0[ky*3+kx] = xs[(y0+ky)*28 + x0 + kx];
                xv1[ky*3+kx] = xs[(y1+ky)*28 + x1 + kx];
                xv2[ky*3+kx] = xs[(y2+ky)*28 + x2 + kx];
            }
        uint wA[4] = {0u,0u,0u,0u}, wB[4] = {0u,0u,0u,0u}, wC[4] = {0u,0u,0u,0u};
        for (int oc = 0; oc < 16; ++oc) {
            float s0 = 0.f, s1 = 0.f, s2 = 0.f;
            #pragma unroll
            for (int k = 0; k < 9; ++k) {
                float w = wf[oc*9 + k];
                s0 = fmaf(xv0[k], w, s0);
                s1 = fmaf(xv1[k], w, s1);
                s2 = fmaf(xv2[k], w, s2);
            }
            bool b0, b1, b2;
            if (__builtin_expect(fabsf(s0) < 1e-3f, 0)) {
                double sd = 0.0;
                for (int k = 0; k < 9; ++k) sd += (double)xv0[k] * (double)wf[oc*9+k];
                b0 = (sd >= 0.0);
            } else b0 = (s0 >= 0.f);
            if (__builtin_expect(fabsf(s1) < 1e-3f, 0)) {
                double sd = 0.0;
                for (int k = 0; k < 9; ++k) sd += (double)xv1[k] * (double)wf[oc*9+k];
                b1 = (sd >= 0.0);
            } else b1 = (s1 >= 0.f);
            if (__builtin_expect(fabsf(s2) < 1e-3f, 0)) {
                double sd = 0.0;
                for (int k = 0; k < 9; ++k) sd += (double)xv2[k] * (double)wf[oc*9+k];
                b2 = (sd >= 0.0);
            } else b2 = (s2 >= 0.f);
            wA[oc>>2] |= (b0 ? 0x01u : 0xFFu) << (8*(oc&3));
            wB[oc>>2] |= (b1 ? 0x01u : 0xFFu) << (8*(oc&3));
            wC[oc>>2] |= (b2 ? 0x01u : 0xFFu) << (8*(oc&3));
        }
        v4i hv;
        hv[0] = (int)wA[0]; hv[1] = (int)wA[1]; hv[2] = (int)wA[2]; hv[3] = (int)wA[3];
        *(v4i*)(h1 + p0*16) = hv;
        hv[0] = (int)wB[0]; hv[1] = (int)wB[1]; hv[2] = (int)wB[2]; hv[3] = (int)wB[3];
        *(v4i*)(h1 + p1*16) = hv;
        if (has2) {
            hv[0] = (int)wC[0]; hv[1] = (int)wC[1]; hv[2] = (int)wC[2]; hv[3] = (int)wC[3];
            *(v4i*)(h1 + p2*16) = hv;
        }
    }
    __syncthreads();

    // ---- conv2 via i8 MFMA: M=576, N=32, K=144 (pad 160) ----
    {
        const v4i* w2bp = (const v4i*)(wsu + WS_W2B);
        v4i b2f[5];
        #pragma unroll
        for (int s = 0; s < 5; ++s) b2f[s] = w2bp[s*64 + l];
        for (int tile = wave; tile < 18; tile += 4) {
            const int m0 = tile * 32;
            const int row = m0 + (l & 31);
            const int y = row / 24, xx = row % 24;
            v16i acc = {0,0,0,0,0,0,0,0,0,0,0,0,0,0,0,0};
            #pragma unroll
            for (int s = 0; s < 5; ++s) {
                int tap = s*2 + half; if (tap > 8) tap = 8;   // B bytes are 0 for tap 9
                int ky = tap / 3, kx = tap - ky*3;
                int pos1 = (y + ky)*26 + (xx + kx);
                v4i a = *(const v4i*)(h1 + pos1*16);
                acc = __builtin_amdgcn_mfma_i32_32x32x32_i8(a, b2f[s], acc, 0, 0, 0);
            }
            const int oc = l & 31;
            #pragma unroll
            for (int r = 0; r < 16; ++r) {
                int rr = m0 + (r & 3) + 8*(r >> 2) + 4*half;
                h2[rr*32 + oc] = (acc[r] >= 0) ? (signed char)1 : (signed char)-1;
            }
        }
    }
    __syncthreads();

    // ---- conv3 via i8 MFMA: M=484 (pad 512), N=32, K=288 ----
    {
        const v4i* w3bp = (const v4i*)(wsu + WS_W3B);
        v4i b3f[9];
        #pragma unroll
        for (int s = 0; s < 9; ++s) b3f[s] = w3bp[s*64 + l];
        for (int tile = wave; tile < 16; tile += 4) {
            const int m0 = tile * 32;
            int row = m0 + (l & 31);
            int pr = (row < 484) ? row : 483;
            const int y = pr / 22, xx = pr % 22;
            v16i acc = {0,0,0,0,0,0,0,0,0,0,0,0,0,0,0,0};
            #pragma unroll
            for (int s = 0; s < 9; ++s) {
                const int ky = s / 3, kx = s - ky*3;
                int pos1 = (y + ky)*24 + (xx + kx);
                v4i a = *(const v4i*)(h2 + pos1*32 + half*16);
                acc = __builtin_amdgcn_mfma_i32_32x32x32_i8(a, b3f[s], acc, 0, 0, 0);
            }
            #pragma unroll
            for (int r = 0; r < 16; ++r) {
                unsigned long long m = __ballot(acc[r] >= 0);
                int ra = m0 + (r & 3) + 8*(r >> 2);
                if (l == 0 && ra < 484) h3[ra] = (uint)m;
                if (l == 1 && ra + 4 < 484) h3[ra + 4] = (uint)(m >> 32);
            }
        }
    }
    __syncthreads();

    // ---- avgpool + FC as binary dot, then log_softmax ----
    int acc10[10];
    #pragma unroll
    for (int o = 0; o < 10; ++o) acc10[o] = 0;
    for (int p = t; p < 484; p += 256) {
        uint h = h3[p];
        const uint* wp = wsu + WS_FC + p;
        #pragma unroll
        for (int o = 0; o < 10; ++o)
            acc10[o] += __popc(h ^ wp[o*484]);
    }
    #pragma unroll
    for (int o = 0; o < 10; ++o) {
        int v = acc10[o];
        v += __shfl_down(v, 32); v += __shfl_down(v, 16);
        v += __shfl_down(v, 8);  v += __shfl_down(v, 4);
        v += __shfl_down(v, 2);  v += __shfl_down(v, 1);
        acc10[o] = v;
    }
    if (l == 0) {
        #pragma unroll
        for (int o = 0; o < 10; ++o) red[wave][o] = acc10[o];
    }
    __syncthreads();
    if (t < 10) {
        int S = red[0][t] + red[1][t] + red[2][t] + red[3][t];
        lg[t] = 0.25f * (float)(15488 - 2*S) + bfc[t];
    }
    __syncthreads();
    if (t < 10) {
        float m = lg[0];
        #pragma unroll
        for (int o = 1; o < 10; ++o) m = fmaxf(m, lg[o]);
        float se = 0.f;
        #pragma unroll
        for (int o = 0; o < 10; ++o) se += expf(lg[o] - m);
        out[(size_t)img*10 + t] = lg[t] - m - logf(se);
    }
}

extern "C" void kernel_launch(void* const* d_in, const int* in_sizes, int n_in,
                              void* d_out, int out_size, void* d_ws, size_t ws_size,
                              hipStream_t stream)
{
    const float* x   = (const float*)d_in[0];
    const float* w1  = (const float*)d_in[1];
    const float* w2  = (const float*)d_in[2];
    const float* w3  = (const float*)d_in[3];
    const float* wfc = (const float*)d_in[4];
    const float* bfc = (const float*)d_in[5];
    float* out = (float*)d_out;
    uint* wsu  = (uint*)d_ws;

    const int B = in_sizes[0] / 784;   // 8192

    hipLaunchKernelGGL(pack_kernel, dim3(23), dim3(256), 0, stream,
                       w1, w2, w3, wfc, wsu);
    hipLaunchKernelGGL(binet_kernel, dim3(B), dim3(256), 0, stream,
                       x, wsu, bfc, out);
}